// Round 1
// 466.204 us; speedup vs baseline: 1.1153x; 1.1153x over previous
//
#include <hip/hip_runtime.h>
#include <cstdint>
#include <cmath>

#define NN 4096
#define FF 512
#define HH 64
#define KSPLIT 8

typedef unsigned short ushort_t;
typedef short bf16x8 __attribute__((ext_vector_type(8)));
typedef float f32x4 __attribute__((ext_vector_type(4)));

// ---------------- threefry2x32 (JAX-compatible, 20 rounds) ----------------
__host__ __device__ __forceinline__ uint32_t rotl32(uint32_t x, int r) {
    return (x << r) | (x >> (32 - r));
}

__host__ __device__ __forceinline__ void threefry2x32(uint32_t ks0, uint32_t ks1,
                                                      uint32_t x0, uint32_t x1,
                                                      uint32_t& o0, uint32_t& o1) {
    uint32_t ks2 = ks0 ^ ks1 ^ 0x1BD11BDAu;
    x0 += ks0; x1 += ks1;
    x0 += x1; x1 = rotl32(x1, 13); x1 ^= x0;
    x0 += x1; x1 = rotl32(x1, 15); x1 ^= x0;
    x0 += x1; x1 = rotl32(x1, 26); x1 ^= x0;
    x0 += x1; x1 = rotl32(x1,  6); x1 ^= x0;
    x0 += ks1; x1 += ks2 + 1u;
    x0 += x1; x1 = rotl32(x1, 17); x1 ^= x0;
    x0 += x1; x1 = rotl32(x1, 29); x1 ^= x0;
    x0 += x1; x1 = rotl32(x1, 16); x1 ^= x0;
    x0 += x1; x1 = rotl32(x1, 24); x1 ^= x0;
    x0 += ks2; x1 += ks0 + 2u;
    x0 += x1; x1 = rotl32(x1, 13); x1 ^= x0;
    x0 += x1; x1 = rotl32(x1, 15); x1 ^= x0;
    x0 += x1; x1 = rotl32(x1, 26); x1 ^= x0;
    x0 += x1; x1 = rotl32(x1,  6); x1 ^= x0;
    x0 += ks0; x1 += ks1 + 3u;
    x0 += x1; x1 = rotl32(x1, 17); x1 ^= x0;
    x0 += x1; x1 = rotl32(x1, 29); x1 ^= x0;
    x0 += x1; x1 = rotl32(x1, 16); x1 ^= x0;
    x0 += x1; x1 = rotl32(x1, 24); x1 ^= x0;
    x0 += ks1; x1 += ks2 + 4u;
    x0 += x1; x1 = rotl32(x1, 13); x1 ^= x0;
    x0 += x1; x1 = rotl32(x1, 15); x1 ^= x0;
    x0 += x1; x1 = rotl32(x1, 26); x1 ^= x0;
    x0 += x1; x1 = rotl32(x1,  6); x1 ^= x0;
    x0 += ks2; x1 += ks0 + 5u;
    o0 = x0; o1 = x1;
}

__device__ __forceinline__ uint32_t jax_bits32(uint32_t k0, uint32_t k1, uint32_t j) {
    uint32_t b0, b1;
    threefry2x32(k0, k1, 0u, j, b0, b1);
    return b0 ^ b1;
}

__device__ __forceinline__ float jax_uniform(uint32_t bits) {
    const float minv = 1e-6f;
    const float maxv = (float)(1.0 - 1e-6);
    const float span = maxv - minv;
    float f = __uint_as_float((bits >> 9) | 0x3f800000u) - 1.0f;
    float u = __fadd_rn(__fmul_rn(f, span), minv);
    return fmaxf(minv, u);
}

// hard Bernoulli-ST forward: 1[ l + logit(u) > 0 ]  <=>  u > 1/(1+e^l)
__device__ __forceinline__ float hard_sample_f(float l, float u) {
    float thr = 1.0f / (1.0f + expf(l));
    return (u > thr) ? 1.0f : 0.0f;
}

__device__ __forceinline__ ushort_t f32_to_bf16_rne(float f) {
    uint32_t x = __float_as_uint(f);
    uint32_t r = (x + 0x7fffu + ((x >> 16) & 1u)) >> 16;
    return (ushort_t)r;
}

// ---------------- pipeline kernels (all fp32) ----------------

// T[4096,64] = x[4096,512] @ Wg[512,64]
__global__ void k_xw(const float* __restrict__ x, const float* __restrict__ Wg,
                     float* __restrict__ T) {
    int col = threadIdx.x;
    int row = blockIdx.x * 4 + threadIdx.y;
    const float* xr = x + row * FF;
    float acc = 0.0f;
    #pragma unroll 4
    for (int k = 0; k < FF; ++k)
        acc += xr[k] * Wg[k * HH + col];
    T[row * HH + col] = acc;
}

// adjT: LDS-tiled f32, K-split partials. partial[s][4096][64]
__global__ void __launch_bounds__(256)
k_adjT2(const float* __restrict__ adj, const float* __restrict__ T,
        float* __restrict__ partial) {
    __shared__ __align__(16) float As[64][68];
    __shared__ __align__(16) float Ts[64][64];
    int t = threadIdx.x;
    int tx = t & 15, ty = t >> 4;
    int r0 = blockIdx.x * 64;
    int kb = blockIdx.y * (NN / KSPLIT);
    float acc[4][4] = {};
    for (int k0 = 0; k0 < NN / KSPLIT; k0 += 64) {
        __syncthreads();
        for (int n = t; n < 1024; n += 256) {
            int rr = n >> 4, kq = n & 15;
            float4 v = *(const float4*)&adj[(size_t)(r0 + rr) * NN + kb + k0 + kq * 4];
            *(float4*)&As[rr][kq * 4] = v;
        }
        for (int n = t; n < 1024; n += 256) {
            int rr = n >> 4, kq = n & 15;
            float4 v = *(const float4*)&T[(size_t)(kb + k0 + rr) * HH + kq * 4];
            *(float4*)&Ts[rr][kq * 4] = v;
        }
        __syncthreads();
        for (int kk = 0; kk < 64; ++kk) {
            float a[4];
            #pragma unroll
            for (int i = 0; i < 4; ++i) a[i] = As[ty * 4 + i][kk];
            float4 bv = *(float4*)&Ts[kk][tx * 4];
            float b[4] = {bv.x, bv.y, bv.z, bv.w};
            #pragma unroll
            for (int i = 0; i < 4; ++i)
                #pragma unroll
                for (int j = 0; j < 4; ++j)
                    acc[i][j] += a[i] * b[j];
        }
    }
    float* P = partial + (size_t)blockIdx.y * NN * HH;
    #pragma unroll
    for (int i = 0; i < 4; ++i) {
        int row = r0 + ty * 4 + i;
        float4 v = {acc[i][0], acc[i][1], acc[i][2], acc[i][3]};
        *(float4*)&P[(size_t)row * HH + tx * 4] = v;
    }
}

// h = relu(sum_s partial[s] + bg)
__global__ void k_hred(const float* __restrict__ partial, const float* __restrict__ bg,
                       float* __restrict__ h) {
    int idx = blockIdx.x * 256 + threadIdx.x;
    float s = 0.0f;
    #pragma unroll
    for (int p = 0; p < KSPLIT; ++p) s += partial[(size_t)p * NN * HH + idx];
    float v = s + bg[idx & (HH - 1)];
    h[idx] = v > 0.0f ? v : 0.0f;
}

// O[4096,64] = relu(A[4096,64] @ W[64,64] + b)
__global__ void k_small64(const float* __restrict__ A, const float* __restrict__ W,
                          const float* __restrict__ b, float* __restrict__ O) {
    __shared__ float Wl[HH][HH];
    int tx = threadIdx.x, ty = threadIdx.y;
    int tid = ty * 64 + tx;
    for (int n = tid; n < HH * HH; n += 256)
        ((float*)Wl)[n] = W[n];
    __syncthreads();
    int row = blockIdx.x * 4 + ty;
    const float* Ar = A + row * HH;
    float acc = 0.0f;
    #pragma unroll
    for (int k = 0; k < HH; ++k) acc += Ar[k] * Wl[k][tx];
    float v = acc + b[tx];
    O[row * HH + tx] = v > 0.0f ? v : 0.0f;
}

// Zb[4096,512] (bf16) = A[4096,64] @ W[64,512] + b
__global__ void k_projZ(const float* __restrict__ A, const float* __restrict__ W,
                        const float* __restrict__ b, ushort_t* __restrict__ Zb) {
    int tx = threadIdx.x, ty = threadIdx.y;
    int row = blockIdx.y * 4 + ty;
    int col = blockIdx.x * 64 + tx;
    const float* Ar = A + row * HH;
    float acc = 0.0f;
    #pragma unroll
    for (int k = 0; k < HH; ++k) acc += Ar[k] * W[k * FF + col];
    Zb[(size_t)row * FF + col] = f32_to_bf16_rne(acc + b[col]);
}

// mask logits + feature-mask sampling fused: xnew = x * mask
__global__ void k_mask(const float* __restrict__ M1, const float* __restrict__ W,
                       const float* __restrict__ b, const float* __restrict__ x,
                       float* __restrict__ xnew, uint32_t k20, uint32_t k21,
                       float Lmin, float Lmax) {
    int tx = threadIdx.x, ty = threadIdx.y;
    int row = blockIdx.y * 4 + ty;
    int col = blockIdx.x * 64 + tx;
    const float* Ar = M1 + row * HH;
    float acc = 0.0f;
    #pragma unroll
    for (int k = 0; k < HH; ++k) acc += Ar[k] * W[k * FF + col];
    float ml = acc + b[col];
    float l = ml < Lmin ? Lmin : (ml > Lmax ? Lmax : ml);
    uint32_t idx = (uint32_t)row * FF + (uint32_t)col;
    float u = jax_uniform(jax_bits32(k20, k21, idx));
    float m = hard_sample_f(l, u);
    xnew[idx] = (m != 0.0f) ? x[idx] : 0.0f;
}

// adj_logits = Zb @ Zb^T via bf16 MFMA.
// FULL-SQUARE version: 1024 blocks (32x32 tile grid of 128x128), no mirror
// writes (all stores row-local and coalesced), fused edge sampling packs
// a_ij into a bitmask (1 bit/edge) + popcount rowsums. z(r,c)==z(c,r)
// bitwise (MFMA k-reduction order is operand-symmetric), and the noise index
// is min*NN+max on both sides, so samples stay symmetric-consistent.
// mfma_f32_16x16x32_bf16 fragments (gfx950 HW-verified):
//   A: m=lane&15, k=(lane>>4)*8+j  (8 contiguous bf16 along k)
//   B: n=lane&15, k=(lane>>4)*8+j
//   D: col=lane&15, row=(lane>>4)*4+reg
__global__ void __launch_bounds__(256)
k_zzt(const ushort_t* __restrict__ Zb, float* __restrict__ out2,
      uint32_t* __restrict__ mask, float* __restrict__ rowsum,
      uint32_t k10, uint32_t k11, float Lmin, float Lmax) {
    __shared__ __align__(16) ushort_t At[128][72];   // +8 pad: 144B stride, 2-way banks (free)
    __shared__ __align__(16) ushort_t Bt[128][72];
    __shared__ int rs_i[128];
    int t = threadIdx.x;
    int lane = t & 63, w = t >> 6;
    int lr = lane & 15, lk = lane >> 4;
    if (t < 128) rs_i[t] = 0;
    int b = blockIdx.x;
    int bi = b >> 5, bj = b & 31;
    int rbase = bi * 128, cbase = bj * 128;
    f32x4 acc[2][8] = {};
    for (int k0 = 0; k0 < FF; k0 += 64) {
        __syncthreads();
        for (int n = t; n < 1024; n += 256) {
            int rr = n >> 3, ck = n & 7;
            *(uint4*)&At[rr][ck * 8] = *(const uint4*)&Zb[(size_t)(rbase + rr) * FF + k0 + ck * 8];
            *(uint4*)&Bt[rr][ck * 8] = *(const uint4*)&Zb[(size_t)(cbase + rr) * FF + k0 + ck * 8];
        }
        __syncthreads();
        #pragma unroll
        for (int ks = 0; ks < 2; ++ks) {
            bf16x8 a0 = *(const bf16x8*)&At[w * 32 + lr][ks * 32 + lk * 8];
            bf16x8 a1 = *(const bf16x8*)&At[w * 32 + 16 + lr][ks * 32 + lk * 8];
            #pragma unroll
            for (int j = 0; j < 8; ++j) {
                bf16x8 bb = *(const bf16x8*)&Bt[j * 16 + lr][ks * 32 + lk * 8];
                acc[0][j] = __builtin_amdgcn_mfma_f32_16x16x32_bf16(a0, bb, acc[0][j], 0, 0, 0);
                acc[1][j] = __builtin_amdgcn_mfma_f32_16x16x32_bf16(a1, bb, acc[1][j], 0, 0, 0);
            }
        }
    }
    // Epilogue: coalesced logits store + sampling -> ballot bit-pack.
    #pragma unroll
    for (int it = 0; it < 2; ++it) {
        #pragma unroll
        for (int reg = 0; reg < 4; ++reg) {
            unsigned long long ball[8];
            int rg = rbase + w * 32 + it * 16 + lk * 4 + reg;
            #pragma unroll
            for (int j = 0; j < 8; ++j) {
                float z = acc[it][j][reg];
                int cg = cbase + j * 16 + lr;
                out2[(size_t)rg * NN + cg] = z;
                float l = z < Lmin ? Lmin : (z > Lmax ? Lmax : z);
                int lo = rg < cg ? rg : cg;
                int hi = rg < cg ? cg : rg;
                uint32_t idx = (uint32_t)lo * NN + (uint32_t)hi;
                float u = jax_uniform(jax_bits32(k10, k11, idx));
                float thr = 1.0f / (1.0f + expf(l));
                int bit = (rg == cg) ? 1 : (u > thr ? 1 : 0);
                ball[j] = __ballot(bit);
            }
            // ballot bit layout: bit(lane) with lane = lk*16+lr, element
            // (row = base+lk*4+reg, col = j*16+lr). 16 lanes assemble the
            // 16 mask words of this (it,reg) slice: lane -> (lkp, wi),
            // word = cols [wi*32, wi*32+32) of row(lkp) = j={2wi,2wi+1}.
            if (lane < 16) {
                int lkp = lane >> 2, wi = lane & 3;
                unsigned long long bl = (wi & 2) ? ((wi & 1) ? ball[6] : ball[4])
                                                 : ((wi & 1) ? ball[2] : ball[0]);
                unsigned long long bh = (wi & 2) ? ((wi & 1) ? ball[7] : ball[5])
                                                 : ((wi & 1) ? ball[3] : ball[1]);
                uint32_t lo16 = (uint32_t)(bl >> (lkp * 16)) & 0xffffu;
                uint32_t hi16 = (uint32_t)(bh >> (lkp * 16)) & 0xffffu;
                uint32_t wv = lo16 | (hi16 << 16);
                int rl = w * 32 + it * 16 + lkp * 4 + reg;
                mask[(size_t)(rbase + rl) * (NN / 32) + (cbase >> 5) + wi] = wv;
                atomicAdd(&rs_i[rl], (int)__popc(wv));
            }
        }
    }
    __syncthreads();
    if (t < 128)
        atomicAdd(&rowsum[rbase + t], (float)rs_i[t]);
}

__global__ void k_deg(const float* __restrict__ rowsum, float* __restrict__ dvec) {
    int i = blockIdx.x * 256 + threadIdx.x;
    dvec[i] = 1.0f / sqrtf(rowsum[i]);
}

// expand bitmask -> adj_norm: out0[r][c] = bit ? d_r*d_c : 0  (diag bit = 1)
__global__ void k_scale2(const uint32_t* __restrict__ mask,
                         const float* __restrict__ dvec, float* __restrict__ out0) {
    size_t idx = ((size_t)blockIdx.x * 256 + threadIdx.x) * 4;
    int r = (int)(idx >> 12);
    int c = (int)(idx & 4095);
    uint32_t wv = mask[idx >> 5];
    int sh = (int)(idx & 31);
    float dr = dvec[r];
    float4 dc = *(const float4*)&dvec[c];
    float4 o;
    o.x = ((wv >> (sh + 0)) & 1u) ? dr * dc.x : 0.0f;
    o.y = ((wv >> (sh + 1)) & 1u) ? dr * dc.y : 0.0f;
    o.z = ((wv >> (sh + 2)) & 1u) ? dr * dc.z : 0.0f;
    o.w = ((wv >> (sh + 3)) & 1u) ? dr * dc.w : 0.0f;
    *(float4*)&out0[idx] = o;
}

// ---------------- launch ----------------
extern "C" void kernel_launch(void* const* d_in, const int* in_sizes, int n_in,
                              void* d_out, int out_size, void* d_ws, size_t ws_size,
                              hipStream_t stream) {
    const float* adj = (const float*)d_in[0];
    const float* x   = (const float*)d_in[1];
    const float* Wg  = (const float*)d_in[2];
    const float* bg  = (const float*)d_in[3];
    const float* Wa1 = (const float*)d_in[4];
    const float* ba1 = (const float*)d_in[5];
    const float* Wa2 = (const float*)d_in[6];
    const float* ba2 = (const float*)d_in[7];
    const float* Wx1 = (const float*)d_in[8];
    const float* bx1 = (const float*)d_in[9];
    const float* Wx2 = (const float*)d_in[10];
    const float* bx2 = (const float*)d_in[11];

    float* out0 = (float*)d_out;                          // adj_norm [N,N]
    float* out1 = out0 + (size_t)NN * NN;                 // x_new [N,F]
    float* out2 = out1 + (size_t)NN * FF;                 // adj_logits [N,N]

    float* T       = (float*)d_ws;                 // [4096,64]   1 MB
    float* h       = T + NN * HH;                  // [4096,64]   1 MB
    float* A1      = h + NN * HH;                  // [4096,64]   1 MB
    float* M1      = A1 + NN * HH;                 // [4096,64]   1 MB
    ushort_t* Zb   = (ushort_t*)(M1 + NN * HH);    // [4096,512] bf16, 4 MB
    float* partial = (float*)(Zb + (size_t)NN * FF); // [8][4096,64] 8 MB
    float* dvec    = partial + (size_t)KSPLIT * NN * HH;
    float* rowsum  = dvec + NN;
    // edge bitmask [4096][128] u32 (2 MB) aliased onto partial (dead after k_hred)
    uint32_t* mask = (uint32_t*)partial;

    uint32_t k1a, k1b, k2a, k2b;
    threefry2x32(0u, 42u, 0u, 0u, k1a, k1b);  // adjacency noise key
    threefry2x32(0u, 42u, 0u, 1u, k2a, k2b);  // feature-mask noise key

    const float Lmax = (float)(std::log(1.0 - 1e-6) - std::log1p(-(1.0 - 1e-6)));
    const float Lmin = (float)(std::log(1e-6) - std::log1p(-1e-6));

    k_xw<<<NN / 4, dim3(64, 4), 0, stream>>>(x, Wg, T);
    k_adjT2<<<dim3(64, KSPLIT), 256, 0, stream>>>(adj, T, partial);
    k_hred<<<NN * HH / 256, 256, 0, stream>>>(partial, bg, h);
    k_small64<<<NN / 4, dim3(64, 4), 0, stream>>>(h, Wa1, ba1, A1);
    k_projZ<<<dim3(FF / 64, NN / 4), dim3(64, 4), 0, stream>>>(A1, Wa2, ba2, Zb);

    hipMemsetAsync(rowsum, 0, NN * sizeof(float), stream);
    k_zzt<<<1024, 256, 0, stream>>>(Zb, out2, mask, rowsum, k1a, k1b, Lmin, Lmax);
    k_deg<<<NN / 256, 256, 0, stream>>>(rowsum, dvec);
    k_scale2<<<NN * NN / 4 / 256, 256, 0, stream>>>(mask, dvec, out0);

    k_small64<<<NN / 4, dim3(64, 4), 0, stream>>>(h, Wx1, bx1, M1);
    k_mask<<<dim3(FF / 64, NN / 4), dim3(64, 4), 0, stream>>>(M1, Wx2, bx2, x, out1,
                                                              k2a, k2b, Lmin, Lmax);
}

// Round 2
// 462.563 us; speedup vs baseline: 1.1241x; 1.0079x over previous
//
#include <hip/hip_runtime.h>
#include <cstdint>
#include <cmath>

#define NN 4096
#define FF 512
#define HH 64
#define KSPLIT 8

typedef unsigned short ushort_t;
typedef short bf16x8 __attribute__((ext_vector_type(8)));
typedef float f32x4 __attribute__((ext_vector_type(4)));

// ---------------- threefry2x32 (JAX-compatible, 20 rounds) ----------------
__host__ __device__ __forceinline__ uint32_t rotl32(uint32_t x, int r) {
    return (x << r) | (x >> (32 - r));
}

__host__ __device__ __forceinline__ void threefry2x32(uint32_t ks0, uint32_t ks1,
                                                      uint32_t x0, uint32_t x1,
                                                      uint32_t& o0, uint32_t& o1) {
    uint32_t ks2 = ks0 ^ ks1 ^ 0x1BD11BDAu;
    x0 += ks0; x1 += ks1;
    x0 += x1; x1 = rotl32(x1, 13); x1 ^= x0;
    x0 += x1; x1 = rotl32(x1, 15); x1 ^= x0;
    x0 += x1; x1 = rotl32(x1, 26); x1 ^= x0;
    x0 += x1; x1 = rotl32(x1,  6); x1 ^= x0;
    x0 += ks1; x1 += ks2 + 1u;
    x0 += x1; x1 = rotl32(x1, 17); x1 ^= x0;
    x0 += x1; x1 = rotl32(x1, 29); x1 ^= x0;
    x0 += x1; x1 = rotl32(x1, 16); x1 ^= x0;
    x0 += x1; x1 = rotl32(x1, 24); x1 ^= x0;
    x0 += ks2; x1 += ks0 + 2u;
    x0 += x1; x1 = rotl32(x1, 13); x1 ^= x0;
    x0 += x1; x1 = rotl32(x1, 15); x1 ^= x0;
    x0 += x1; x1 = rotl32(x1, 26); x1 ^= x0;
    x0 += x1; x1 = rotl32(x1,  6); x1 ^= x0;
    x0 += ks0; x1 += ks1 + 3u;
    x0 += x1; x1 = rotl32(x1, 17); x1 ^= x0;
    x0 += x1; x1 = rotl32(x1, 29); x1 ^= x0;
    x0 += x1; x1 = rotl32(x1, 16); x1 ^= x0;
    x0 += x1; x1 = rotl32(x1, 24); x1 ^= x0;
    x0 += ks1; x1 += ks2 + 4u;
    x0 += x1; x1 = rotl32(x1, 13); x1 ^= x0;
    x0 += x1; x1 = rotl32(x1, 15); x1 ^= x0;
    x0 += x1; x1 = rotl32(x1, 26); x1 ^= x0;
    x0 += x1; x1 = rotl32(x1,  6); x1 ^= x0;
    x0 += ks2; x1 += ks0 + 5u;
    o0 = x0; o1 = x1;
}

__device__ __forceinline__ uint32_t jax_bits32(uint32_t k0, uint32_t k1, uint32_t j) {
    uint32_t b0, b1;
    threefry2x32(k0, k1, 0u, j, b0, b1);
    return b0 ^ b1;
}

__device__ __forceinline__ float jax_uniform(uint32_t bits) {
    const float minv = 1e-6f;
    const float maxv = (float)(1.0 - 1e-6);
    const float span = maxv - minv;
    float f = __uint_as_float((bits >> 9) | 0x3f800000u) - 1.0f;
    float u = __fadd_rn(__fmul_rn(f, span), minv);
    return fmaxf(minv, u);
}

// hard Bernoulli-ST forward: 1[ l + logit(u) > 0 ]  <=>  u > 1/(1+e^l)
__device__ __forceinline__ float hard_sample_f(float l, float u) {
    float thr = 1.0f / (1.0f + expf(l));
    return (u > thr) ? 1.0f : 0.0f;
}

__device__ __forceinline__ ushort_t f32_to_bf16_rne(float f) {
    uint32_t x = __float_as_uint(f);
    uint32_t r = (x + 0x7fffu + ((x >> 16) & 1u)) >> 16;
    return (ushort_t)r;
}

// ---------------- pipeline kernels (all fp32) ----------------

// T[4096,64] = x[4096,512] @ Wg[512,64]
__global__ void k_xw(const float* __restrict__ x, const float* __restrict__ Wg,
                     float* __restrict__ T) {
    int col = threadIdx.x;
    int row = blockIdx.x * 4 + threadIdx.y;
    const float* xr = x + row * FF;
    float acc = 0.0f;
    #pragma unroll 4
    for (int k = 0; k < FF; ++k)
        acc += xr[k] * Wg[k * HH + col];
    T[row * HH + col] = acc;
}

// adjT: LDS-tiled f32, K-split partials. partial[s][4096][64]
__global__ void __launch_bounds__(256)
k_adjT2(const float* __restrict__ adj, const float* __restrict__ T,
        float* __restrict__ partial) {
    __shared__ __align__(16) float As[64][68];
    __shared__ __align__(16) float Ts[64][64];
    int t = threadIdx.x;
    int tx = t & 15, ty = t >> 4;
    int r0 = blockIdx.x * 64;
    int kb = blockIdx.y * (NN / KSPLIT);
    float acc[4][4] = {};
    for (int k0 = 0; k0 < NN / KSPLIT; k0 += 64) {
        __syncthreads();
        for (int n = t; n < 1024; n += 256) {
            int rr = n >> 4, kq = n & 15;
            float4 v = *(const float4*)&adj[(size_t)(r0 + rr) * NN + kb + k0 + kq * 4];
            *(float4*)&As[rr][kq * 4] = v;
        }
        for (int n = t; n < 1024; n += 256) {
            int rr = n >> 4, kq = n & 15;
            float4 v = *(const float4*)&T[(size_t)(kb + k0 + rr) * HH + kq * 4];
            *(float4*)&Ts[rr][kq * 4] = v;
        }
        __syncthreads();
        for (int kk = 0; kk < 64; ++kk) {
            float a[4];
            #pragma unroll
            for (int i = 0; i < 4; ++i) a[i] = As[ty * 4 + i][kk];
            float4 bv = *(float4*)&Ts[kk][tx * 4];
            float b[4] = {bv.x, bv.y, bv.z, bv.w};
            #pragma unroll
            for (int i = 0; i < 4; ++i)
                #pragma unroll
                for (int j = 0; j < 4; ++j)
                    acc[i][j] += a[i] * b[j];
        }
    }
    float* P = partial + (size_t)blockIdx.y * NN * HH;
    #pragma unroll
    for (int i = 0; i < 4; ++i) {
        int row = r0 + ty * 4 + i;
        float4 v = {acc[i][0], acc[i][1], acc[i][2], acc[i][3]};
        *(float4*)&P[(size_t)row * HH + tx * 4] = v;
    }
}

// h = relu(sum_s partial[s] + bg)
__global__ void k_hred(const float* __restrict__ partial, const float* __restrict__ bg,
                       float* __restrict__ h) {
    int idx = blockIdx.x * 256 + threadIdx.x;
    float s = 0.0f;
    #pragma unroll
    for (int p = 0; p < KSPLIT; ++p) s += partial[(size_t)p * NN * HH + idx];
    float v = s + bg[idx & (HH - 1)];
    h[idx] = v > 0.0f ? v : 0.0f;
}

// O[4096,64] = relu(A[4096,64] @ W[64,64] + b)
__global__ void k_small64(const float* __restrict__ A, const float* __restrict__ W,
                          const float* __restrict__ b, float* __restrict__ O) {
    __shared__ float Wl[HH][HH];
    int tx = threadIdx.x, ty = threadIdx.y;
    int tid = ty * 64 + tx;
    for (int n = tid; n < HH * HH; n += 256)
        ((float*)Wl)[n] = W[n];
    __syncthreads();
    int row = blockIdx.x * 4 + ty;
    const float* Ar = A + row * HH;
    float acc = 0.0f;
    #pragma unroll
    for (int k = 0; k < HH; ++k) acc += Ar[k] * Wl[k][tx];
    float v = acc + b[tx];
    O[row * HH + tx] = v > 0.0f ? v : 0.0f;
}

// Zb[4096,512] (bf16) = A[4096,64] @ W[64,512] + b
__global__ void k_projZ(const float* __restrict__ A, const float* __restrict__ W,
                        const float* __restrict__ b, ushort_t* __restrict__ Zb) {
    int tx = threadIdx.x, ty = threadIdx.y;
    int row = blockIdx.y * 4 + ty;
    int col = blockIdx.x * 64 + tx;
    const float* Ar = A + row * HH;
    float acc = 0.0f;
    #pragma unroll
    for (int k = 0; k < HH; ++k) acc += Ar[k] * W[k * FF + col];
    Zb[(size_t)row * FF + col] = f32_to_bf16_rne(acc + b[col]);
}

// mask logits + feature-mask sampling fused: xnew = x * mask
__global__ void k_mask(const float* __restrict__ M1, const float* __restrict__ W,
                       const float* __restrict__ b, const float* __restrict__ x,
                       float* __restrict__ xnew, uint32_t k20, uint32_t k21,
                       float Lmin, float Lmax) {
    int tx = threadIdx.x, ty = threadIdx.y;
    int row = blockIdx.y * 4 + ty;
    int col = blockIdx.x * 64 + tx;
    const float* Ar = M1 + row * HH;
    float acc = 0.0f;
    #pragma unroll
    for (int k = 0; k < HH; ++k) acc += Ar[k] * W[k * FF + col];
    float ml = acc + b[col];
    float l = ml < Lmin ? Lmin : (ml > Lmax ? Lmax : ml);
    uint32_t idx = (uint32_t)row * FF + (uint32_t)col;
    float u = jax_uniform(jax_bits32(k20, k21, idx));
    float m = hard_sample_f(l, u);
    xnew[idx] = (m != 0.0f) ? x[idx] : 0.0f;
}

// adj_logits = Zb @ Zb^T via bf16 MFMA — PURE GEMM (sampling de-fused).
// Same tiling / MFMA order as the fused version => bitwise-identical out2.
// mfma_f32_16x16x32_bf16 fragments (gfx950 HW-verified):
//   A: m=lane&15, k=(lane>>4)*8+j  (8 contiguous bf16 along k)
//   B: n=lane&15, k=(lane>>4)*8+j
//   D: col=lane&15, row=(lane>>4)*4+reg
__global__ void __launch_bounds__(256)
k_zzt_gemm(const ushort_t* __restrict__ Zb, float* __restrict__ out2) {
    __shared__ __align__(16) ushort_t At[128][72];   // +8 pad: 144B stride, 2-way banks (free)
    __shared__ __align__(16) ushort_t Bt[128][72];
    int t = threadIdx.x;
    int lane = t & 63, w = t >> 6;
    int lr = lane & 15, lk = lane >> 4;
    int b = blockIdx.x;
    int bi = b >> 5, bj = b & 31;
    int rbase = bi * 128, cbase = bj * 128;
    f32x4 acc[2][8] = {};
    for (int k0 = 0; k0 < FF; k0 += 64) {
        __syncthreads();
        for (int n = t; n < 1024; n += 256) {
            int rr = n >> 3, ck = n & 7;
            *(uint4*)&At[rr][ck * 8] = *(const uint4*)&Zb[(size_t)(rbase + rr) * FF + k0 + ck * 8];
            *(uint4*)&Bt[rr][ck * 8] = *(const uint4*)&Zb[(size_t)(cbase + rr) * FF + k0 + ck * 8];
        }
        __syncthreads();
        #pragma unroll
        for (int ks = 0; ks < 2; ++ks) {
            bf16x8 a0 = *(const bf16x8*)&At[w * 32 + lr][ks * 32 + lk * 8];
            bf16x8 a1 = *(const bf16x8*)&At[w * 32 + 16 + lr][ks * 32 + lk * 8];
            #pragma unroll
            for (int j = 0; j < 8; ++j) {
                bf16x8 bb = *(const bf16x8*)&Bt[j * 16 + lr][ks * 32 + lk * 8];
                acc[0][j] = __builtin_amdgcn_mfma_f32_16x16x32_bf16(a0, bb, acc[0][j], 0, 0, 0);
                acc[1][j] = __builtin_amdgcn_mfma_f32_16x16x32_bf16(a1, bb, acc[1][j], 0, 0, 0);
            }
        }
    }
    #pragma unroll
    for (int it = 0; it < 2; ++it) {
        int rg = rbase + w * 32 + it * 16 + lk * 4;
        #pragma unroll
        for (int reg = 0; reg < 4; ++reg) {
            #pragma unroll
            for (int j = 0; j < 8; ++j) {
                out2[(size_t)(rg + reg) * NN + cbase + j * 16 + lr] = acc[it][j][reg];
            }
        }
    }
}

// Edge sampling over logits: one thread per 32-column mask word.
// Fully parallel: no LDS, no barriers, no ballot. Reads out2 coalesced
// (128B/thread), packs 32 sample bits locally, popcount -> 1 atomic/wave.
// Noise index = min*N+max on both sides => symmetric-consistent (same RNG
// scheme as the harness-verified fused version).
__global__ void __launch_bounds__(256)
k_sample(const float* __restrict__ out2, uint32_t* __restrict__ mask,
         float* __restrict__ rowsum, uint32_t k10, uint32_t k11,
         float Lmin, float Lmax) {
    int g = blockIdx.x * 256 + threadIdx.x;
    int r = g >> 7;            // row
    int wd = g & 127;          // 32-col word within row
    const float* zr = out2 + (size_t)r * NN + wd * 32;
    uint32_t word = 0;
    #pragma unroll
    for (int q = 0; q < 8; ++q) {
        float4 zv = *(const float4*)&zr[q * 4];
        float za[4] = {zv.x, zv.y, zv.z, zv.w};
        #pragma unroll
        for (int e4 = 0; e4 < 4; ++e4) {
            int e = q * 4 + e4;
            int c = wd * 32 + e;
            float z = za[e4];
            float l = z < Lmin ? Lmin : (z > Lmax ? Lmax : z);
            int lo = r < c ? r : c;
            int hi = r < c ? c : r;
            uint32_t idx = (uint32_t)lo * NN + (uint32_t)hi;
            float u = jax_uniform(jax_bits32(k10, k11, idx));
            float thr = 1.0f / (1.0f + expf(l));
            uint32_t bit = (r == c) ? 1u : (u > thr ? 1u : 0u);
            word |= bit << e;
        }
    }
    mask[g] = word;
    int pc = __popc(word);
    // all 64 lanes of a wave share the same row r (64 divides 128)
    #pragma unroll
    for (int off = 32; off; off >>= 1) pc += __shfl_down(pc, off);
    if ((threadIdx.x & 63) == 0) atomicAdd(&rowsum[r], (float)pc);
}

__global__ void k_deg(const float* __restrict__ rowsum, float* __restrict__ dvec) {
    int i = blockIdx.x * 256 + threadIdx.x;
    dvec[i] = 1.0f / sqrtf(rowsum[i]);
}

// expand bitmask -> adj_norm: out0[r][c] = bit ? d_r*d_c : 0  (diag bit = 1)
__global__ void k_scale2(const uint32_t* __restrict__ mask,
                         const float* __restrict__ dvec, float* __restrict__ out0) {
    size_t idx = ((size_t)blockIdx.x * 256 + threadIdx.x) * 4;
    int r = (int)(idx >> 12);
    int c = (int)(idx & 4095);
    uint32_t wv = mask[idx >> 5];
    int sh = (int)(idx & 31);
    float dr = dvec[r];
    float4 dc = *(const float4*)&dvec[c];
    float4 o;
    o.x = ((wv >> (sh + 0)) & 1u) ? dr * dc.x : 0.0f;
    o.y = ((wv >> (sh + 1)) & 1u) ? dr * dc.y : 0.0f;
    o.z = ((wv >> (sh + 2)) & 1u) ? dr * dc.z : 0.0f;
    o.w = ((wv >> (sh + 3)) & 1u) ? dr * dc.w : 0.0f;
    *(float4*)&out0[idx] = o;
}

// ---------------- launch ----------------
extern "C" void kernel_launch(void* const* d_in, const int* in_sizes, int n_in,
                              void* d_out, int out_size, void* d_ws, size_t ws_size,
                              hipStream_t stream) {
    const float* adj = (const float*)d_in[0];
    const float* x   = (const float*)d_in[1];
    const float* Wg  = (const float*)d_in[2];
    const float* bg  = (const float*)d_in[3];
    const float* Wa1 = (const float*)d_in[4];
    const float* ba1 = (const float*)d_in[5];
    const float* Wa2 = (const float*)d_in[6];
    const float* ba2 = (const float*)d_in[7];
    const float* Wx1 = (const float*)d_in[8];
    const float* bx1 = (const float*)d_in[9];
    const float* Wx2 = (const float*)d_in[10];
    const float* bx2 = (const float*)d_in[11];

    float* out0 = (float*)d_out;                          // adj_norm [N,N]
    float* out1 = out0 + (size_t)NN * NN;                 // x_new [N,F]
    float* out2 = out1 + (size_t)NN * FF;                 // adj_logits [N,N]

    float* T       = (float*)d_ws;                 // [4096,64]   1 MB
    float* h       = T + NN * HH;                  // [4096,64]   1 MB
    float* A1      = h + NN * HH;                  // [4096,64]   1 MB
    float* M1      = A1 + NN * HH;                 // [4096,64]   1 MB
    ushort_t* Zb   = (ushort_t*)(M1 + NN * HH);    // [4096,512] bf16, 4 MB
    float* partial = (float*)(Zb + (size_t)NN * FF); // [8][4096,64] 8 MB
    float* dvec    = partial + (size_t)KSPLIT * NN * HH;
    float* rowsum  = dvec + NN;
    // edge bitmask [4096][128] u32 (2 MB) aliased onto partial (dead after k_hred)
    uint32_t* mask = (uint32_t*)partial;

    uint32_t k1a, k1b, k2a, k2b;
    threefry2x32(0u, 42u, 0u, 0u, k1a, k1b);  // adjacency noise key
    threefry2x32(0u, 42u, 0u, 1u, k2a, k2b);  // feature-mask noise key

    const float Lmax = (float)(std::log(1.0 - 1e-6) - std::log1p(-(1.0 - 1e-6)));
    const float Lmin = (float)(std::log(1e-6) - std::log1p(-1e-6));

    k_xw<<<NN / 4, dim3(64, 4), 0, stream>>>(x, Wg, T);
    k_adjT2<<<dim3(64, KSPLIT), 256, 0, stream>>>(adj, T, partial);
    k_hred<<<NN * HH / 256, 256, 0, stream>>>(partial, bg, h);
    k_small64<<<NN / 4, dim3(64, 4), 0, stream>>>(h, Wa1, ba1, A1);
    k_projZ<<<dim3(FF / 64, NN / 4), dim3(64, 4), 0, stream>>>(A1, Wa2, ba2, Zb);

    k_zzt_gemm<<<1024, 256, 0, stream>>>(Zb, out2);

    hipMemsetAsync(rowsum, 0, NN * sizeof(float), stream);
    k_sample<<<NN * NN / 32 / 256, 256, 0, stream>>>(out2, mask, rowsum,
                                                     k1a, k1b, Lmin, Lmax);
    k_deg<<<NN / 256, 256, 0, stream>>>(rowsum, dvec);
    k_scale2<<<NN * NN / 4 / 256, 256, 0, stream>>>(mask, dvec, out0);

    k_small64<<<NN / 4, dim3(64, 4), 0, stream>>>(h, Wx1, bx1, M1);
    k_mask<<<dim3(FF / 64, NN / 4), dim3(64, 4), 0, stream>>>(M1, Wx2, bx2, x, out1,
                                                              k2a, k2b, Lmin, Lmax);
}

// Round 3
// 442.973 us; speedup vs baseline: 1.1738x; 1.0442x over previous
//
#include <hip/hip_runtime.h>
#include <cstdint>
#include <cmath>

#define NN 4096
#define FF 512
#define HH 64
#define KSPLIT 8

typedef unsigned short ushort_t;
typedef short bf16x8 __attribute__((ext_vector_type(8)));
typedef float f32x4 __attribute__((ext_vector_type(4)));

// ---------------- threefry2x32 (JAX-compatible, 20 rounds) ----------------
__host__ __device__ __forceinline__ uint32_t rotl32(uint32_t x, int r) {
    return (x << r) | (x >> (32 - r));
}

__host__ __device__ __forceinline__ void threefry2x32(uint32_t ks0, uint32_t ks1,
                                                      uint32_t x0, uint32_t x1,
                                                      uint32_t& o0, uint32_t& o1) {
    uint32_t ks2 = ks0 ^ ks1 ^ 0x1BD11BDAu;
    x0 += ks0; x1 += ks1;
    x0 += x1; x1 = rotl32(x1, 13); x1 ^= x0;
    x0 += x1; x1 = rotl32(x1, 15); x1 ^= x0;
    x0 += x1; x1 = rotl32(x1, 26); x1 ^= x0;
    x0 += x1; x1 = rotl32(x1,  6); x1 ^= x0;
    x0 += ks1; x1 += ks2 + 1u;
    x0 += x1; x1 = rotl32(x1, 17); x1 ^= x0;
    x0 += x1; x1 = rotl32(x1, 29); x1 ^= x0;
    x0 += x1; x1 = rotl32(x1, 16); x1 ^= x0;
    x0 += x1; x1 = rotl32(x1, 24); x1 ^= x0;
    x0 += ks2; x1 += ks0 + 2u;
    x0 += x1; x1 = rotl32(x1, 13); x1 ^= x0;
    x0 += x1; x1 = rotl32(x1, 15); x1 ^= x0;
    x0 += x1; x1 = rotl32(x1, 26); x1 ^= x0;
    x0 += x1; x1 = rotl32(x1,  6); x1 ^= x0;
    x0 += ks0; x1 += ks1 + 3u;
    x0 += x1; x1 = rotl32(x1, 17); x1 ^= x0;
    x0 += x1; x1 = rotl32(x1, 29); x1 ^= x0;
    x0 += x1; x1 = rotl32(x1, 16); x1 ^= x0;
    x0 += x1; x1 = rotl32(x1, 24); x1 ^= x0;
    x0 += ks1; x1 += ks2 + 4u;
    x0 += x1; x1 = rotl32(x1, 13); x1 ^= x0;
    x0 += x1; x1 = rotl32(x1, 15); x1 ^= x0;
    x0 += x1; x1 = rotl32(x1, 26); x1 ^= x0;
    x0 += x1; x1 = rotl32(x1,  6); x1 ^= x0;
    x0 += ks2; x1 += ks0 + 5u;
    o0 = x0; o1 = x1;
}

__device__ __forceinline__ uint32_t jax_bits32(uint32_t k0, uint32_t k1, uint32_t j) {
    uint32_t b0, b1;
    threefry2x32(k0, k1, 0u, j, b0, b1);
    return b0 ^ b1;
}

__device__ __forceinline__ float jax_uniform(uint32_t bits) {
    const float minv = 1e-6f;
    const float maxv = (float)(1.0 - 1e-6);
    const float span = maxv - minv;
    float f = __uint_as_float((bits >> 9) | 0x3f800000u) - 1.0f;
    float u = __fadd_rn(__fmul_rn(f, span), minv);
    return fmaxf(minv, u);
}

// hard Bernoulli-ST forward: 1[ l + logit(u) > 0 ]  <=>  u > 1/(1+e^l)
__device__ __forceinline__ float hard_sample_f(float l, float u) {
    float thr = 1.0f / (1.0f + expf(l));
    return (u > thr) ? 1.0f : 0.0f;
}

__device__ __forceinline__ ushort_t f32_to_bf16_rne(float f) {
    uint32_t x = __float_as_uint(f);
    uint32_t r = (x + 0x7fffu + ((x >> 16) & 1u)) >> 16;
    return (ushort_t)r;
}

// ---------------- pipeline kernels (all fp32) ----------------

// T[4096,64] = x[4096,512] @ Wg[512,64]
__global__ void k_xw(const float* __restrict__ x, const float* __restrict__ Wg,
                     float* __restrict__ T) {
    int col = threadIdx.x;
    int row = blockIdx.x * 4 + threadIdx.y;
    const float* xr = x + row * FF;
    float acc = 0.0f;
    #pragma unroll 4
    for (int k = 0; k < FF; ++k)
        acc += xr[k] * Wg[k * HH + col];
    T[row * HH + col] = acc;
}

// adjT: LDS-tiled f32, K-split partials. partial[s][4096][64]
__global__ void __launch_bounds__(256)
k_adjT2(const float* __restrict__ adj, const float* __restrict__ T,
        float* __restrict__ partial) {
    __shared__ __align__(16) float As[64][68];
    __shared__ __align__(16) float Ts[64][64];
    int t = threadIdx.x;
    int tx = t & 15, ty = t >> 4;
    int r0 = blockIdx.x * 64;
    int kb = blockIdx.y * (NN / KSPLIT);
    float acc[4][4] = {};
    for (int k0 = 0; k0 < NN / KSPLIT; k0 += 64) {
        __syncthreads();
        for (int n = t; n < 1024; n += 256) {
            int rr = n >> 4, kq = n & 15;
            float4 v = *(const float4*)&adj[(size_t)(r0 + rr) * NN + kb + k0 + kq * 4];
            *(float4*)&As[rr][kq * 4] = v;
        }
        for (int n = t; n < 1024; n += 256) {
            int rr = n >> 4, kq = n & 15;
            float4 v = *(const float4*)&T[(size_t)(kb + k0 + rr) * HH + kq * 4];
            *(float4*)&Ts[rr][kq * 4] = v;
        }
        __syncthreads();
        for (int kk = 0; kk < 64; ++kk) {
            float a[4];
            #pragma unroll
            for (int i = 0; i < 4; ++i) a[i] = As[ty * 4 + i][kk];
            float4 bv = *(float4*)&Ts[kk][tx * 4];
            float b[4] = {bv.x, bv.y, bv.z, bv.w};
            #pragma unroll
            for (int i = 0; i < 4; ++i)
                #pragma unroll
                for (int j = 0; j < 4; ++j)
                    acc[i][j] += a[i] * b[j];
        }
    }
    float* P = partial + (size_t)blockIdx.y * NN * HH;
    #pragma unroll
    for (int i = 0; i < 4; ++i) {
        int row = r0 + ty * 4 + i;
        float4 v = {acc[i][0], acc[i][1], acc[i][2], acc[i][3]};
        *(float4*)&P[(size_t)row * HH + tx * 4] = v;
    }
}

// h = relu(sum_s partial[s] + bg)
__global__ void k_hred(const float* __restrict__ partial, const float* __restrict__ bg,
                       float* __restrict__ h) {
    int idx = blockIdx.x * 256 + threadIdx.x;
    float s = 0.0f;
    #pragma unroll
    for (int p = 0; p < KSPLIT; ++p) s += partial[(size_t)p * NN * HH + idx];
    float v = s + bg[idx & (HH - 1)];
    h[idx] = v > 0.0f ? v : 0.0f;
}

// O[4096,64] = relu(A[4096,64] @ W[64,64] + b)
__global__ void k_small64(const float* __restrict__ A, const float* __restrict__ W,
                          const float* __restrict__ b, float* __restrict__ O) {
    __shared__ float Wl[HH][HH];
    int tx = threadIdx.x, ty = threadIdx.y;
    int tid = ty * 64 + tx;
    for (int n = tid; n < HH * HH; n += 256)
        ((float*)Wl)[n] = W[n];
    __syncthreads();
    int row = blockIdx.x * 4 + ty;
    const float* Ar = A + row * HH;
    float acc = 0.0f;
    #pragma unroll
    for (int k = 0; k < HH; ++k) acc += Ar[k] * Wl[k][tx];
    float v = acc + b[tx];
    O[row * HH + tx] = v > 0.0f ? v : 0.0f;
}

// Zb[4096,512] (bf16) = A[4096,64] @ W[64,512] + b
__global__ void k_projZ(const float* __restrict__ A, const float* __restrict__ W,
                        const float* __restrict__ b, ushort_t* __restrict__ Zb) {
    int tx = threadIdx.x, ty = threadIdx.y;
    int row = blockIdx.y * 4 + ty;
    int col = blockIdx.x * 64 + tx;
    const float* Ar = A + row * HH;
    float acc = 0.0f;
    #pragma unroll
    for (int k = 0; k < HH; ++k) acc += Ar[k] * W[k * FF + col];
    Zb[(size_t)row * FF + col] = f32_to_bf16_rne(acc + b[col]);
}

// mask logits + feature-mask sampling fused: xnew = x * mask
__global__ void k_mask(const float* __restrict__ M1, const float* __restrict__ W,
                       const float* __restrict__ b, const float* __restrict__ x,
                       float* __restrict__ xnew, uint32_t k20, uint32_t k21,
                       float Lmin, float Lmax) {
    int tx = threadIdx.x, ty = threadIdx.y;
    int row = blockIdx.y * 4 + ty;
    int col = blockIdx.x * 64 + tx;
    const float* Ar = M1 + row * HH;
    float acc = 0.0f;
    #pragma unroll
    for (int k = 0; k < HH; ++k) acc += Ar[k] * W[k * FF + col];
    float ml = acc + b[col];
    float l = ml < Lmin ? Lmin : (ml > Lmax ? Lmax : ml);
    uint32_t idx = (uint32_t)row * FF + (uint32_t)col;
    float u = jax_uniform(jax_bits32(k20, k21, idx));
    float m = hard_sample_f(l, u);
    xnew[idx] = (m != 0.0f) ? x[idx] : 0.0f;
}

// adj_logits = Zb @ Zb^T via bf16 MFMA — TRIANGULAR tiles (528 blocks).
// Z@Z^T is symmetric: compute tile (bi,bj) with bj>=bi, store it row-major
// directly, and for bi!=bj ALSO store the (bj,bi) mirror tile — transposed
// through LDS in 128x32 chunks (reusing dead At/Bt space) so the mirror
// store is row-major coalesced (round-0's column-order mirror caused 1.57x
// write amplification; this avoids it).
// mfma_f32_16x16x32_bf16 fragments (gfx950 HW-verified):
//   A: m=lane&15, k=(lane>>4)*8+j  (8 contiguous bf16 along k)
//   B: n=lane&15, k=(lane>>4)*8+j
//   D: col=lane&15, row=(lane>>4)*4+reg
__global__ void __launch_bounds__(256)
k_zzt_gemm_tri(const ushort_t* __restrict__ Zb, float* __restrict__ out2) {
    __shared__ __align__(16) union {
        struct { ushort_t At[128][72]; ushort_t Bt[128][72]; } s;  // 36.9 KB
        float Tls[32][132];                                         // 16.9 KB
    } sm;
    int t = threadIdx.x;
    int lane = t & 63, w = t >> 6;
    int lr = lane & 15, lk = lane >> 4;
    int b = blockIdx.x, bi = 0;
    while (b >= 32 - bi) { b -= 32 - bi; ++bi; }
    int bj = bi + b;
    int rbase = bi * 128, cbase = bj * 128;
    f32x4 acc[2][8] = {};
    for (int k0 = 0; k0 < FF; k0 += 64) {
        __syncthreads();
        for (int n = t; n < 1024; n += 256) {
            int rr = n >> 3, ck = n & 7;
            *(uint4*)&sm.s.At[rr][ck * 8] = *(const uint4*)&Zb[(size_t)(rbase + rr) * FF + k0 + ck * 8];
            *(uint4*)&sm.s.Bt[rr][ck * 8] = *(const uint4*)&Zb[(size_t)(cbase + rr) * FF + k0 + ck * 8];
        }
        __syncthreads();
        #pragma unroll
        for (int ks = 0; ks < 2; ++ks) {
            bf16x8 a0 = *(const bf16x8*)&sm.s.At[w * 32 + lr][ks * 32 + lk * 8];
            bf16x8 a1 = *(const bf16x8*)&sm.s.At[w * 32 + 16 + lr][ks * 32 + lk * 8];
            #pragma unroll
            for (int j = 0; j < 8; ++j) {
                bf16x8 bb = *(const bf16x8*)&sm.s.Bt[j * 16 + lr][ks * 32 + lk * 8];
                acc[0][j] = __builtin_amdgcn_mfma_f32_16x16x32_bf16(a0, bb, acc[0][j], 0, 0, 0);
                acc[1][j] = __builtin_amdgcn_mfma_f32_16x16x32_bf16(a1, bb, acc[1][j], 0, 0, 0);
            }
        }
    }
    // direct (bi,bj) tile store — row-major coalesced
    #pragma unroll
    for (int it = 0; it < 2; ++it) {
        int rg = rbase + w * 32 + it * 16 + lk * 4;
        #pragma unroll
        for (int reg = 0; reg < 4; ++reg)
            #pragma unroll
            for (int j = 0; j < 8; ++j)
                out2[(size_t)(rg + reg) * NN + cbase + j * 16 + lr] = acc[it][j][reg];
    }
    if (bi != bj) {
        // mirror (bj,bi) tile: transpose 32-col chunks through LDS.
        // chunk g covers original cols [g*32, g*32+32) = j in {2g, 2g+1}.
        #pragma unroll
        for (int g = 0; g < 4; ++g) {
            __syncthreads();  // also guards At/Bt -> Tls aliasing at g=0
            #pragma unroll
            for (int it = 0; it < 2; ++it)
                #pragma unroll
                for (int jp = 0; jp < 2; ++jp)
                    #pragma unroll
                    for (int reg = 0; reg < 4; ++reg)
                        sm.Tls[jp * 16 + lr][w * 32 + it * 16 + lk * 4 + reg] =
                            acc[it][g * 2 + jp][reg];
            __syncthreads();
            #pragma unroll
            for (int r4 = 0; r4 < 4; ++r4) {
                int tr = r4 * 8 + (t >> 5);     // transposed row = original col
                int tc = (t & 31) * 4;          // transposed col = original row
                float4 v = *(const float4*)&sm.Tls[tr][tc];
                *(float4*)&out2[(size_t)(cbase + g * 32 + tr) * NN + rbase + tc] = v;
            }
        }
    }
}

// Edge sampling — TRIANGULAR tiles (528 blocks of 128x128).
// Bits are symmetric by construction (idx = min*N+max): compute only the
// upper-tri tile, write its mask words, then bit-transpose the 128x128 bit
// tile in LDS and write the mirror words. Bit-identical to the full-square
// version (same idx/threefry/compare), half the threefry volume.
__global__ void __launch_bounds__(256)
k_sample_tri(const float* __restrict__ out2, uint32_t* __restrict__ mask,
             float* __restrict__ rowsum, uint32_t k10, uint32_t k11,
             float Lmin, float Lmax) {
    __shared__ uint32_t Wl[128][5];   // 4 words/row + pad (bank spread)
    __shared__ int rs[128], cs[128];
    int t = threadIdx.x;
    int b = blockIdx.x, bi = 0;
    while (b >= 32 - bi) { b -= 32 - bi; ++bi; }
    int bj = bi + b;
    int rbase = bi * 128, cbase = bj * 128;
    if (t < 128) { rs[t] = 0; cs[t] = 0; }
    __syncthreads();
    int rr = t >> 1;
    int r = rbase + rr;
    int rowacc = 0;
    #pragma unroll
    for (int wi = 0; wi < 2; ++wi) {
        int wc = (t & 1) * 2 + wi;
        const float* zr = out2 + (size_t)r * NN + cbase + wc * 32;
        uint32_t word = 0;
        #pragma unroll
        for (int q = 0; q < 8; ++q) {
            float4 zv = *(const float4*)&zr[q * 4];
            float za[4] = {zv.x, zv.y, zv.z, zv.w};
            #pragma unroll
            for (int e4 = 0; e4 < 4; ++e4) {
                int e = q * 4 + e4;
                int c = cbase + wc * 32 + e;
                float z = za[e4];
                float l = z < Lmin ? Lmin : (z > Lmax ? Lmax : z);
                int lo = r < c ? r : c;
                int hi = r < c ? c : r;
                uint32_t idx = (uint32_t)lo * NN + (uint32_t)hi;
                float u = jax_uniform(jax_bits32(k10, k11, idx));
                float thr = 1.0f / (1.0f + expf(l));
                uint32_t bit = (r == c) ? 1u : (u > thr ? 1u : 0u);
                word |= bit << e;
            }
        }
        Wl[rr][wc] = word;
        mask[(size_t)r * (NN / 32) + ((cbase >> 5) + wc)] = word;
        rowacc += __popc(word);
    }
    atomicAdd(&rs[rr], rowacc);
    __syncthreads();
    if (bi != bj) {
        // mirror: T-word at (row cbase+cc, word (rbase>>5)+wr), bit b =
        // original bit(rbase+wr*32+b, cbase+cc) = Wl[wr*32+b][cc>>5] bit (cc&31)
        int cc = t >> 1;
        int colacc = 0;
        #pragma unroll
        for (int wi = 0; wi < 2; ++wi) {
            int wr = (t & 1) * 2 + wi;
            uint32_t tw = 0;
            #pragma unroll
            for (int bb = 0; bb < 32; ++bb)
                tw |= ((Wl[wr * 32 + bb][cc >> 5] >> (cc & 31)) & 1u) << bb;
            mask[(size_t)(cbase + cc) * (NN / 32) + ((rbase >> 5) + wr)] = tw;
            colacc += __popc(tw);
        }
        atomicAdd(&cs[cc], colacc);
    }
    __syncthreads();
    if (t < 128) {
        atomicAdd(&rowsum[rbase + t], (float)rs[t]);
        if (bi != bj) atomicAdd(&rowsum[cbase + t], (float)cs[t]);
    }
}

__global__ void k_deg(const float* __restrict__ rowsum, float* __restrict__ dvec) {
    int i = blockIdx.x * 256 + threadIdx.x;
    dvec[i] = 1.0f / sqrtf(rowsum[i]);
}

// expand bitmask -> adj_norm: out0[r][c] = bit ? d_r*d_c : 0  (diag bit = 1)
__global__ void k_scale2(const uint32_t* __restrict__ mask,
                         const float* __restrict__ dvec, float* __restrict__ out0) {
    size_t idx = ((size_t)blockIdx.x * 256 + threadIdx.x) * 4;
    int r = (int)(idx >> 12);
    int c = (int)(idx & 4095);
    uint32_t wv = mask[idx >> 5];
    int sh = (int)(idx & 31);
    float dr = dvec[r];
    float4 dc = *(const float4*)&dvec[c];
    float4 o;
    o.x = ((wv >> (sh + 0)) & 1u) ? dr * dc.x : 0.0f;
    o.y = ((wv >> (sh + 1)) & 1u) ? dr * dc.y : 0.0f;
    o.z = ((wv >> (sh + 2)) & 1u) ? dr * dc.z : 0.0f;
    o.w = ((wv >> (sh + 3)) & 1u) ? dr * dc.w : 0.0f;
    *(float4*)&out0[idx] = o;
}

// ---------------- launch ----------------
extern "C" void kernel_launch(void* const* d_in, const int* in_sizes, int n_in,
                              void* d_out, int out_size, void* d_ws, size_t ws_size,
                              hipStream_t stream) {
    const float* adj = (const float*)d_in[0];
    const float* x   = (const float*)d_in[1];
    const float* Wg  = (const float*)d_in[2];
    const float* bg  = (const float*)d_in[3];
    const float* Wa1 = (const float*)d_in[4];
    const float* ba1 = (const float*)d_in[5];
    const float* Wa2 = (const float*)d_in[6];
    const float* ba2 = (const float*)d_in[7];
    const float* Wx1 = (const float*)d_in[8];
    const float* bx1 = (const float*)d_in[9];
    const float* Wx2 = (const float*)d_in[10];
    const float* bx2 = (const float*)d_in[11];

    float* out0 = (float*)d_out;                          // adj_norm [N,N]
    float* out1 = out0 + (size_t)NN * NN;                 // x_new [N,F]
    float* out2 = out1 + (size_t)NN * FF;                 // adj_logits [N,N]

    float* T       = (float*)d_ws;                 // [4096,64]   1 MB
    float* h       = T + NN * HH;                  // [4096,64]   1 MB
    float* A1      = h + NN * HH;                  // [4096,64]   1 MB
    float* M1      = A1 + NN * HH;                 // [4096,64]   1 MB
    ushort_t* Zb   = (ushort_t*)(M1 + NN * HH);    // [4096,512] bf16, 4 MB
    float* partial = (float*)(Zb + (size_t)NN * FF); // [8][4096,64] 8 MB
    float* dvec    = partial + (size_t)KSPLIT * NN * HH;
    float* rowsum  = dvec + NN;
    // edge bitmask [4096][128] u32 (2 MB) aliased onto partial (dead after k_hred)
    uint32_t* mask = (uint32_t*)partial;

    uint32_t k1a, k1b, k2a, k2b;
    threefry2x32(0u, 42u, 0u, 0u, k1a, k1b);  // adjacency noise key
    threefry2x32(0u, 42u, 0u, 1u, k2a, k2b);  // feature-mask noise key

    const float Lmax = (float)(std::log(1.0 - 1e-6) - std::log1p(-(1.0 - 1e-6)));
    const float Lmin = (float)(std::log(1e-6) - std::log1p(-1e-6));

    k_xw<<<NN / 4, dim3(64, 4), 0, stream>>>(x, Wg, T);
    k_adjT2<<<dim3(64, KSPLIT), 256, 0, stream>>>(adj, T, partial);
    k_hred<<<NN * HH / 256, 256, 0, stream>>>(partial, bg, h);
    k_small64<<<NN / 4, dim3(64, 4), 0, stream>>>(h, Wa1, ba1, A1);
    k_projZ<<<dim3(FF / 64, NN / 4), dim3(64, 4), 0, stream>>>(A1, Wa2, ba2, Zb);

    k_zzt_gemm_tri<<<528, 256, 0, stream>>>(Zb, out2);

    hipMemsetAsync(rowsum, 0, NN * sizeof(float), stream);
    k_sample_tri<<<528, 256, 0, stream>>>(out2, mask, rowsum, k1a, k1b, Lmin, Lmax);
    k_deg<<<NN / 256, 256, 0, stream>>>(rowsum, dvec);
    k_scale2<<<NN * NN / 4 / 256, 256, 0, stream>>>(mask, dvec, out0);

    k_small64<<<NN / 4, dim3(64, 4), 0, stream>>>(h, Wx1, bx1, M1);
    k_mask<<<dim3(FF / 64, NN / 4), dim3(64, 4), 0, stream>>>(M1, Wx2, bx2, x, out1,
                                                              k2a, k2b, Lmin, Lmax);
}

// Round 4
// 393.893 us; speedup vs baseline: 1.3200x; 1.1246x over previous
//
#include <hip/hip_runtime.h>
#include <cstdint>
#include <cmath>

#define NN 4096
#define FF 512
#define HH 64
#define KSPLIT 8

typedef unsigned short ushort_t;
typedef short bf16x8 __attribute__((ext_vector_type(8)));
typedef float f32x4 __attribute__((ext_vector_type(4)));

// ---------------- threefry2x32 (JAX-compatible, 20 rounds) ----------------
__host__ __device__ __forceinline__ uint32_t rotl32(uint32_t x, int r) {
    return (x << r) | (x >> (32 - r));
}

__host__ __device__ __forceinline__ void threefry2x32(uint32_t ks0, uint32_t ks1,
                                                      uint32_t x0, uint32_t x1,
                                                      uint32_t& o0, uint32_t& o1) {
    uint32_t ks2 = ks0 ^ ks1 ^ 0x1BD11BDAu;
    x0 += ks0; x1 += ks1;
    x0 += x1; x1 = rotl32(x1, 13); x1 ^= x0;
    x0 += x1; x1 = rotl32(x1, 15); x1 ^= x0;
    x0 += x1; x1 = rotl32(x1, 26); x1 ^= x0;
    x0 += x1; x1 = rotl32(x1,  6); x1 ^= x0;
    x0 += ks1; x1 += ks2 + 1u;
    x0 += x1; x1 = rotl32(x1, 17); x1 ^= x0;
    x0 += x1; x1 = rotl32(x1, 29); x1 ^= x0;
    x0 += x1; x1 = rotl32(x1, 16); x1 ^= x0;
    x0 += x1; x1 = rotl32(x1, 24); x1 ^= x0;
    x0 += ks2; x1 += ks0 + 2u;
    x0 += x1; x1 = rotl32(x1, 13); x1 ^= x0;
    x0 += x1; x1 = rotl32(x1, 15); x1 ^= x0;
    x0 += x1; x1 = rotl32(x1, 26); x1 ^= x0;
    x0 += x1; x1 = rotl32(x1,  6); x1 ^= x0;
    x0 += ks0; x1 += ks1 + 3u;
    x0 += x1; x1 = rotl32(x1, 17); x1 ^= x0;
    x0 += x1; x1 = rotl32(x1, 29); x1 ^= x0;
    x0 += x1; x1 = rotl32(x1, 16); x1 ^= x0;
    x0 += x1; x1 = rotl32(x1, 24); x1 ^= x0;
    x0 += ks1; x1 += ks2 + 4u;
    x0 += x1; x1 = rotl32(x1, 13); x1 ^= x0;
    x0 += x1; x1 = rotl32(x1, 15); x1 ^= x0;
    x0 += x1; x1 = rotl32(x1, 26); x1 ^= x0;
    x0 += x1; x1 = rotl32(x1,  6); x1 ^= x0;
    x0 += ks2; x1 += ks0 + 5u;
    o0 = x0; o1 = x1;
}

__device__ __forceinline__ uint32_t jax_bits32(uint32_t k0, uint32_t k1, uint32_t j) {
    uint32_t b0, b1;
    threefry2x32(k0, k1, 0u, j, b0, b1);
    return b0 ^ b1;
}

__device__ __forceinline__ float jax_uniform(uint32_t bits) {
    const float minv = 1e-6f;
    const float maxv = (float)(1.0 - 1e-6);
    const float span = maxv - minv;
    float f = __uint_as_float((bits >> 9) | 0x3f800000u) - 1.0f;
    float u = __fadd_rn(__fmul_rn(f, span), minv);
    return fmaxf(minv, u);
}

// hard Bernoulli-ST forward: 1[ l + logit(u) > 0 ]  <=>  u > 1/(1+e^l)
__device__ __forceinline__ float hard_sample_f(float l, float u) {
    float thr = 1.0f / (1.0f + expf(l));
    return (u > thr) ? 1.0f : 0.0f;
}

__device__ __forceinline__ ushort_t f32_to_bf16_rne(float f) {
    uint32_t x = __float_as_uint(f);
    uint32_t r = (x + 0x7fffu + ((x >> 16) & 1u)) >> 16;
    return (ushort_t)r;
}

// ---------------- pipeline kernels ----------------

// Tt[64,4096] (bf16, transposed) = (x[4096,512] @ Wg[512,64])^T
// Transposed+bf16 so k_adjT_mfma's B-fragment reads are k-contiguous.
__global__ void k_xw(const float* __restrict__ x, const float* __restrict__ Wg,
                     ushort_t* __restrict__ Tt) {
    __shared__ ushort_t Tls[4][64];
    int col = threadIdx.x, ty = threadIdx.y;
    int row = blockIdx.x * 4 + ty;
    const float* xr = x + row * FF;
    float acc = 0.0f;
    #pragma unroll 4
    for (int k = 0; k < FF; ++k)
        acc += xr[k] * Wg[k * HH + col];
    Tls[ty][col] = f32_to_bf16_rne(acc);
    __syncthreads();
    int t = ty * 64 + col;
    if (t < 64) {
        uint2 v;
        ushort_t* p = (ushort_t*)&v;
        p[0] = Tls[0][t]; p[1] = Tls[1][t]; p[2] = Tls[2][t]; p[3] = Tls[3][t];
        *(uint2*)&Tt[(size_t)t * NN + blockIdx.x * 4] = v;  // 8B packed store
    }
}

// partial[s][4096][64] += adj(bf16-cvt)[*,Kslice] @ T[Kslice,*] via MFMA.
// adj staged fp32->bf16 on the fly (adj read exactly once, 64 MB stream).
// Fragments (same HW-verified pattern as k_zzt_gemm_tri):
//   A: m=lane&15, k=(lane>>4)*8+j ; B: n=lane&15, k contiguous ;
//   D: col=lane&15, row=(lane>>4)*4+reg
__global__ void __launch_bounds__(256)
k_adjT_mfma(const float* __restrict__ adj, const ushort_t* __restrict__ Tt,
            float* __restrict__ partial) {
    __shared__ __align__(16) ushort_t As[64][72];
    __shared__ __align__(16) ushort_t Tl[64][72];
    int t = threadIdx.x;
    int lane = t & 63, w = t >> 6;
    int lr = lane & 15, lk = lane >> 4;
    int r0 = blockIdx.x * 64;
    int kb = blockIdx.y * (NN / KSPLIT);
    f32x4 acc[4] = {};
    for (int k0 = 0; k0 < NN / KSPLIT; k0 += 64) {
        __syncthreads();
        // stage adj 64x64 fp32 -> bf16
        #pragma unroll
        for (int i = 0; i < 4; ++i) {
            int idx = t + i * 256;            // 1024 float4-groups
            int rr = idx >> 4;
            int kq = (idx & 15) * 4;
            float4 v = *(const float4*)&adj[(size_t)(r0 + rr) * NN + kb + k0 + kq];
            uint32_t lo = (uint32_t)f32_to_bf16_rne(v.x) | ((uint32_t)f32_to_bf16_rne(v.y) << 16);
            uint32_t hi = (uint32_t)f32_to_bf16_rne(v.z) | ((uint32_t)f32_to_bf16_rne(v.w) << 16);
            uint2 pk = {lo, hi};
            *(uint2*)&As[rr][kq] = pk;
        }
        // stage Tt slice [64 cols][64 k] (already bf16, k-contiguous)
        #pragma unroll
        for (int i = 0; i < 2; ++i) {
            int idx = t + i * 256;            // 512 uint4-groups
            int cc = idx >> 3;
            int kq = (idx & 7) * 8;
            *(uint4*)&Tl[cc][kq] = *(const uint4*)&Tt[(size_t)cc * NN + kb + k0 + kq];
        }
        __syncthreads();
        #pragma unroll
        for (int ks = 0; ks < 2; ++ks) {
            bf16x8 a = *(const bf16x8*)&As[w * 16 + lr][ks * 32 + lk * 8];
            #pragma unroll
            for (int c = 0; c < 4; ++c) {
                bf16x8 bb = *(const bf16x8*)&Tl[c * 16 + lr][ks * 32 + lk * 8];
                acc[c] = __builtin_amdgcn_mfma_f32_16x16x32_bf16(a, bb, acc[c], 0, 0, 0);
            }
        }
    }
    float* P = partial + (size_t)blockIdx.y * NN * HH;
    #pragma unroll
    for (int c = 0; c < 4; ++c)
        #pragma unroll
        for (int reg = 0; reg < 4; ++reg)
            P[(size_t)(r0 + w * 16 + lk * 4 + reg) * HH + c * 16 + lr] = acc[c][reg];
}

// h = relu(sum_s partial[s] + bg)
__global__ void k_hred(const float* __restrict__ partial, const float* __restrict__ bg,
                       float* __restrict__ h) {
    int idx = blockIdx.x * 256 + threadIdx.x;
    float s = 0.0f;
    #pragma unroll
    for (int p = 0; p < KSPLIT; ++p) s += partial[(size_t)p * NN * HH + idx];
    float v = s + bg[idx & (HH - 1)];
    h[idx] = v > 0.0f ? v : 0.0f;
}

// Fused MLPA: Zb[4096,512](bf16) = (relu(h@W1+b1)) @ W2 + b2, 8 rows/block.
__global__ void __launch_bounds__(256)
k_mlpZ(const float* __restrict__ h, const float* __restrict__ W1,
       const float* __restrict__ b1, const float* __restrict__ W2,
       const float* __restrict__ b2, ushort_t* __restrict__ Zb) {
    __shared__ float W1l[HH][HH];
    __shared__ float A1l[8][HH];
    __shared__ float hl[8][HH];
    int t = threadIdx.x;
    int r0 = blockIdx.x * 8;
    for (int n = t; n < HH * HH; n += 256) ((float*)W1l)[n] = W1[n];
    for (int n = t; n < 8 * HH; n += 256) ((float*)hl)[n] = h[r0 * HH + n];
    __syncthreads();
    {
        int col = t & 63;
        int rb = t >> 6;
        #pragma unroll
        for (int rr = 0; rr < 2; ++rr) {
            int row = rb * 2 + rr;
            float acc = b1[col];
            #pragma unroll
            for (int k = 0; k < HH; ++k) acc += hl[row][k] * W1l[k][col];
            A1l[row][col] = acc > 0.0f ? acc : 0.0f;
        }
    }
    __syncthreads();
    #pragma unroll
    for (int p = 0; p < 2; ++p) {
        int col = p * 256 + t;
        float wc[HH];
        #pragma unroll
        for (int k = 0; k < HH; ++k) wc[k] = W2[k * FF + col];
        float bb = b2[col];
        #pragma unroll
        for (int row = 0; row < 8; ++row) {
            float acc = bb;
            #pragma unroll
            for (int k = 0; k < HH; ++k) acc += A1l[row][k] * wc[k];
            Zb[(size_t)(r0 + row) * FF + col] = f32_to_bf16_rne(acc);
        }
    }
}

// Fused MLPX + feature-mask sampling: xnew = x * mask(relu(h@Wx1+bx1)@Wx2+bx2)
__global__ void __launch_bounds__(256)
k_mlpM(const float* __restrict__ h, const float* __restrict__ W1,
       const float* __restrict__ b1, const float* __restrict__ W2,
       const float* __restrict__ b2, const float* __restrict__ x,
       float* __restrict__ xnew, uint32_t k20, uint32_t k21,
       float Lmin, float Lmax) {
    __shared__ float W1l[HH][HH];
    __shared__ float A1l[8][HH];
    __shared__ float hl[8][HH];
    int t = threadIdx.x;
    int r0 = blockIdx.x * 8;
    for (int n = t; n < HH * HH; n += 256) ((float*)W1l)[n] = W1[n];
    for (int n = t; n < 8 * HH; n += 256) ((float*)hl)[n] = h[r0 * HH + n];
    __syncthreads();
    {
        int col = t & 63;
        int rb = t >> 6;
        #pragma unroll
        for (int rr = 0; rr < 2; ++rr) {
            int row = rb * 2 + rr;
            float acc = b1[col];
            #pragma unroll
            for (int k = 0; k < HH; ++k) acc += hl[row][k] * W1l[k][col];
            A1l[row][col] = acc > 0.0f ? acc : 0.0f;
        }
    }
    __syncthreads();
    #pragma unroll
    for (int p = 0; p < 2; ++p) {
        int col = p * 256 + t;
        float wc[HH];
        #pragma unroll
        for (int k = 0; k < HH; ++k) wc[k] = W2[k * FF + col];
        float bb = b2[col];
        #pragma unroll
        for (int row = 0; row < 8; ++row) {
            float acc = bb;
            #pragma unroll
            for (int k = 0; k < HH; ++k) acc += A1l[row][k] * wc[k];
            float ml = acc;
            float l = ml < Lmin ? Lmin : (ml > Lmax ? Lmax : ml);
            uint32_t idx = (uint32_t)(r0 + row) * FF + (uint32_t)col;
            float u = jax_uniform(jax_bits32(k20, k21, idx));
            float m = hard_sample_f(l, u);
            size_t gi = (size_t)(r0 + row) * FF + col;
            xnew[gi] = (m != 0.0f) ? x[gi] : 0.0f;
        }
    }
}

// adj_logits = Zb @ Zb^T via bf16 MFMA — TRIANGULAR tiles (528 blocks).
// Mirror tile transposed through LDS in 32-col chunks (row-major coalesced).
__global__ void __launch_bounds__(256)
k_zzt_gemm_tri(const ushort_t* __restrict__ Zb, float* __restrict__ out2) {
    __shared__ __align__(16) union {
        struct { ushort_t At[128][72]; ushort_t Bt[128][72]; } s;
        float Tls[32][132];
    } sm;
    int t = threadIdx.x;
    int lane = t & 63, w = t >> 6;
    int lr = lane & 15, lk = lane >> 4;
    int b = blockIdx.x, bi = 0;
    while (b >= 32 - bi) { b -= 32 - bi; ++bi; }
    int bj = bi + b;
    int rbase = bi * 128, cbase = bj * 128;
    f32x4 acc[2][8] = {};
    for (int k0 = 0; k0 < FF; k0 += 64) {
        __syncthreads();
        for (int n = t; n < 1024; n += 256) {
            int rr = n >> 3, ck = n & 7;
            *(uint4*)&sm.s.At[rr][ck * 8] = *(const uint4*)&Zb[(size_t)(rbase + rr) * FF + k0 + ck * 8];
            *(uint4*)&sm.s.Bt[rr][ck * 8] = *(const uint4*)&Zb[(size_t)(cbase + rr) * FF + k0 + ck * 8];
        }
        __syncthreads();
        #pragma unroll
        for (int ks = 0; ks < 2; ++ks) {
            bf16x8 a0 = *(const bf16x8*)&sm.s.At[w * 32 + lr][ks * 32 + lk * 8];
            bf16x8 a1 = *(const bf16x8*)&sm.s.At[w * 32 + 16 + lr][ks * 32 + lk * 8];
            #pragma unroll
            for (int j = 0; j < 8; ++j) {
                bf16x8 bb = *(const bf16x8*)&sm.s.Bt[j * 16 + lr][ks * 32 + lk * 8];
                acc[0][j] = __builtin_amdgcn_mfma_f32_16x16x32_bf16(a0, bb, acc[0][j], 0, 0, 0);
                acc[1][j] = __builtin_amdgcn_mfma_f32_16x16x32_bf16(a1, bb, acc[1][j], 0, 0, 0);
            }
        }
    }
    #pragma unroll
    for (int it = 0; it < 2; ++it) {
        int rg = rbase + w * 32 + it * 16 + lk * 4;
        #pragma unroll
        for (int reg = 0; reg < 4; ++reg)
            #pragma unroll
            for (int j = 0; j < 8; ++j)
                out2[(size_t)(rg + reg) * NN + cbase + j * 16 + lr] = acc[it][j][reg];
    }
    if (bi != bj) {
        #pragma unroll
        for (int g = 0; g < 4; ++g) {
            __syncthreads();
            #pragma unroll
            for (int it = 0; it < 2; ++it)
                #pragma unroll
                for (int jp = 0; jp < 2; ++jp)
                    #pragma unroll
                    for (int reg = 0; reg < 4; ++reg)
                        sm.Tls[jp * 16 + lr][w * 32 + it * 16 + lk * 4 + reg] =
                            acc[it][g * 2 + jp][reg];
            __syncthreads();
            #pragma unroll
            for (int r4 = 0; r4 < 4; ++r4) {
                int tr = r4 * 8 + (t >> 5);
                int tc = (t & 31) * 4;
                float4 v = *(const float4*)&sm.Tls[tr][tc];
                *(float4*)&out2[(size_t)(cbase + g * 32 + tr) * NN + rbase + tc] = v;
            }
        }
    }
}

// Edge sampling — TRIANGULAR tiles, 512 threads (1 mask word / thread).
__global__ void __launch_bounds__(512)
k_sample_tri(const float* __restrict__ out2, uint32_t* __restrict__ mask,
             float* __restrict__ rowsum, uint32_t k10, uint32_t k11,
             float Lmin, float Lmax) {
    __shared__ uint32_t Wl[128][5];
    __shared__ int rs[128], cs[128];
    int t = threadIdx.x;
    int b = blockIdx.x, bi = 0;
    while (b >= 32 - bi) { b -= 32 - bi; ++bi; }
    int bj = bi + b;
    int rbase = bi * 128, cbase = bj * 128;
    if (t < 128) { rs[t] = 0; cs[t] = 0; }
    __syncthreads();
    int rr = t >> 2, wc = t & 3;
    int r = rbase + rr;
    const float* zr = out2 + (size_t)r * NN + cbase + wc * 32;
    uint32_t word = 0;
    #pragma unroll
    for (int q = 0; q < 8; ++q) {
        float4 zv = *(const float4*)&zr[q * 4];
        float za[4] = {zv.x, zv.y, zv.z, zv.w};
        #pragma unroll
        for (int e4 = 0; e4 < 4; ++e4) {
            int e = q * 4 + e4;
            int c = cbase + wc * 32 + e;
            float z = za[e4];
            float l = z < Lmin ? Lmin : (z > Lmax ? Lmax : z);
            int lo = r < c ? r : c;
            int hi = r < c ? c : r;
            uint32_t idx = (uint32_t)lo * NN + (uint32_t)hi;
            float u = jax_uniform(jax_bits32(k10, k11, idx));
            float thr = 1.0f / (1.0f + expf(l));
            uint32_t bit = (r == c) ? 1u : (u > thr ? 1u : 0u);
            word |= bit << e;
        }
    }
    Wl[rr][wc] = word;
    mask[(size_t)r * (NN / 32) + ((cbase >> 5) + wc)] = word;
    atomicAdd(&rs[rr], (int)__popc(word));
    __syncthreads();
    if (bi != bj) {
        int cc = t >> 2, wr = t & 3;
        uint32_t tw = 0;
        #pragma unroll
        for (int bb = 0; bb < 32; ++bb)
            tw |= ((Wl[wr * 32 + bb][cc >> 5] >> (cc & 31)) & 1u) << bb;
        mask[(size_t)(cbase + cc) * (NN / 32) + ((rbase >> 5) + wr)] = tw;
        atomicAdd(&cs[cc], (int)__popc(tw));
    }
    __syncthreads();
    if (t < 128) {
        atomicAdd(&rowsum[rbase + t], (float)rs[t]);
        if (bi != bj) atomicAdd(&rowsum[cbase + t], (float)cs[t]);
    }
}

// expand bitmask -> adj_norm with inline degree: out0[r][c] = bit ? d_r*d_c : 0
// d_i = 1/sqrtf(rowsum[i]) — bitwise-identical to the old k_deg expression.
__global__ void k_scale3(const uint32_t* __restrict__ mask,
                         const float* __restrict__ rowsum, float* __restrict__ out0) {
    size_t idx = ((size_t)blockIdx.x * 256 + threadIdx.x) * 4;
    int r = (int)(idx >> 12);
    int c = (int)(idx & 4095);
    uint32_t wv = mask[idx >> 5];
    int sh = (int)(idx & 31);
    float dr = 1.0f / sqrtf(rowsum[r]);
    float4 rc = *(const float4*)&rowsum[c];
    float4 o;
    o.x = ((wv >> (sh + 0)) & 1u) ? dr * (1.0f / sqrtf(rc.x)) : 0.0f;
    o.y = ((wv >> (sh + 1)) & 1u) ? dr * (1.0f / sqrtf(rc.y)) : 0.0f;
    o.z = ((wv >> (sh + 2)) & 1u) ? dr * (1.0f / sqrtf(rc.z)) : 0.0f;
    o.w = ((wv >> (sh + 3)) & 1u) ? dr * (1.0f / sqrtf(rc.w)) : 0.0f;
    *(float4*)&out0[idx] = o;
}

// ---------------- launch ----------------
extern "C" void kernel_launch(void* const* d_in, const int* in_sizes, int n_in,
                              void* d_out, int out_size, void* d_ws, size_t ws_size,
                              hipStream_t stream) {
    const float* adj = (const float*)d_in[0];
    const float* x   = (const float*)d_in[1];
    const float* Wg  = (const float*)d_in[2];
    const float* bg  = (const float*)d_in[3];
    const float* Wa1 = (const float*)d_in[4];
    const float* ba1 = (const float*)d_in[5];
    const float* Wa2 = (const float*)d_in[6];
    const float* ba2 = (const float*)d_in[7];
    const float* Wx1 = (const float*)d_in[8];
    const float* bx1 = (const float*)d_in[9];
    const float* Wx2 = (const float*)d_in[10];
    const float* bx2 = (const float*)d_in[11];

    float* out0 = (float*)d_out;                          // adj_norm [N,N]
    float* out1 = out0 + (size_t)NN * NN;                 // x_new [N,F]
    float* out2 = out1 + (size_t)NN * FF;                 // adj_logits [N,N]

    ushort_t* Tt   = (ushort_t*)d_ws;                       // [64,4096] bf16, 512 KB
    float* h       = (float*)((char*)d_ws + (1 << 20));     // [4096,64]  1 MB
    ushort_t* Zb   = (ushort_t*)(h + NN * HH);              // [4096,512] bf16, 4 MB
    float* partial = (float*)((char*)Zb + (size_t)NN * FF * 2); // [8][4096,64] 8 MB
    float* rowsum  = partial + (size_t)KSPLIT * NN * HH;    // [4096]
    // edge bitmask [4096][128] u32 (2 MB) aliased onto partial (dead after k_hred)
    uint32_t* mask = (uint32_t*)partial;

    uint32_t k1a, k1b, k2a, k2b;
    threefry2x32(0u, 42u, 0u, 0u, k1a, k1b);  // adjacency noise key
    threefry2x32(0u, 42u, 0u, 1u, k2a, k2b);  // feature-mask noise key

    const float Lmax = (float)(std::log(1.0 - 1e-6) - std::log1p(-(1.0 - 1e-6)));
    const float Lmin = (float)(std::log(1e-6) - std::log1p(-1e-6));

    k_xw<<<NN / 4, dim3(64, 4), 0, stream>>>(x, Wg, Tt);
    k_adjT_mfma<<<dim3(64, KSPLIT), 256, 0, stream>>>(adj, Tt, partial);
    k_hred<<<NN * HH / 256, 256, 0, stream>>>(partial, bg, h);
    k_mlpZ<<<NN / 8, 256, 0, stream>>>(h, Wa1, ba1, Wa2, ba2, Zb);

    k_zzt_gemm_tri<<<528, 256, 0, stream>>>(Zb, out2);

    hipMemsetAsync(rowsum, 0, NN * sizeof(float), stream);
    k_sample_tri<<<528, 512, 0, stream>>>(out2, mask, rowsum, k1a, k1b, Lmin, Lmax);
    k_scale3<<<NN * NN / 4 / 256, 256, 0, stream>>>(mask, rowsum, out0);

    k_mlpM<<<NN / 8, 256, 0, stream>>>(h, Wx1, bx1, Wx2, bx2, x, out1,
                                       k2a, k2b, Lmin, Lmax);
}